// Round 1
// 1123.638 us; speedup vs baseline: 1.1686x; 1.1686x over previous
//
#include <hip/hip_runtime.h>

// ---------------------------------------------------------------------------
// Problem: mini transformer fwd. B=4 T=1024 E=1024 H=16 HS=64 D=1024 V=32000
// Outputs: logits [4096,32000] fp32, then loss scalar (d_out flat, 131072001)
// ---------------------------------------------------------------------------

typedef __bf16 bf16x8 __attribute__((ext_vector_type(8)));
typedef float f32x4 __attribute__((ext_vector_type(4)));
typedef unsigned short u16;

#define MFMA16(a, b, c) __builtin_amdgcn_mfma_f32_16x16x32_bf16(a, b, c, 0, 0, 0)
#define SCHED_FENCE() __builtin_amdgcn_sched_barrier(0)
#define SBAR()                        \
    do {                              \
        SCHED_FENCE();                \
        __builtin_amdgcn_s_barrier(); \
        SCHED_FENCE();                \
    } while (0)
#define VMW(N) asm volatile("s_waitcnt vmcnt(" #N ")" ::: "memory")

__device__ __forceinline__ u16 f2bf(float f) {
    union { float f; unsigned int u; } v; v.f = f;
    unsigned int r = v.u + 0x7fffu + ((v.u >> 16) & 1u);
    return (u16)(r >> 16);
}

__device__ __forceinline__ void gld16(const u16* g, u16* l) {
    // stages 16B per lane; LDS dest must be wave-uniform base + lane*16 (it is)
    __builtin_amdgcn_global_load_lds((__attribute__((address_space(1))) void*)g,
                                     (__attribute__((address_space(3))) void*)l,
                                     16, 0, 0);
}

// ---------------------------------------------------------------------------
// 1) embedding: h[bt][e] = tok_emb[x[bt]][e] + pos_emb[bt%1024][e]  (bf16 out)
// ---------------------------------------------------------------------------
__global__ void embed_kernel(const int* __restrict__ x, const float* __restrict__ tok,
                             const float* __restrict__ pos, u16* __restrict__ h) {
    int bt = blockIdx.x;
    int t = bt & 1023;
    int row = x[bt];
    const float* te = tok + (size_t)row * 1024;
    const float* pe = pos + (size_t)t * 1024;
    int c = threadIdx.x * 4;
    float4 a = *(const float4*)(te + c);
    float4 b = *(const float4*)(pe + c);
    union { u16 s[4]; uint2 v; } o;
    o.s[0] = f2bf(a.x + b.x); o.s[1] = f2bf(a.y + b.y);
    o.s[2] = f2bf(a.z + b.z); o.s[3] = f2bf(a.w + b.w);
    *(uint2*)(h + (size_t)bt * 1024 + c) = o.v;
}

// ---------------------------------------------------------------------------
// 2) transpose fp32 [R][C] -> bf16 [C][R]   (batched; tiles 64x64)
// ---------------------------------------------------------------------------
__global__ void transpose_f32_bf16(const float* __restrict__ src, u16* __restrict__ dst,
                                   int R, int C) {
    __shared__ float tile[64][65];
    const float* s = src + (size_t)blockIdx.z * R * C;
    u16* d = dst + (size_t)blockIdx.z * R * C;
    int r0 = blockIdx.x * 64, c0 = blockIdx.y * 64;
    int tr = threadIdx.x >> 2, tg = threadIdx.x & 3;
#pragma unroll
    for (int i = 0; i < 4; i++) {
        float4 v = *(const float4*)(s + (size_t)(r0 + tr) * C + c0 + tg * 16 + i * 4);
        tile[tr][tg * 16 + i * 4 + 0] = v.x;
        tile[tr][tg * 16 + i * 4 + 1] = v.y;
        tile[tr][tg * 16 + i * 4 + 2] = v.z;
        tile[tr][tg * 16 + i * 4 + 3] = v.w;
    }
    __syncthreads();
    union { u16 s[16]; uint4 v[2]; } pk;
#pragma unroll
    for (int i = 0; i < 16; i++) pk.s[i] = f2bf(tile[tg * 16 + i][tr]);
    u16* dp = d + (size_t)(c0 + tr) * R + r0 + tg * 16;
    *(uint4*)(dp) = pk.v[0];
    *(uint4*)(dp + 8) = pk.v[1];
}

// ---------------------------------------------------------------------------
// 3) GEMM: C[M,N] = A[M,K] @ Bt[N,K]^T   bf16 in, fp32 acc
//    MODE 0: write bf16; 1: +bias, relu, bf16
//    128x128 tile, BK=64, 4 waves (2x2 of 64x64), 16x16x32 MFMA
//    (kept for the small GEMMs: qkv and ff)
// ---------------------------------------------------------------------------
template <int MODE>
__global__ __launch_bounds__(256, 2) void gemm_bt(const u16* __restrict__ A,
                                                  const u16* __restrict__ Bt,
                                                  void* __restrict__ Cout,
                                                  const float* __restrict__ bias,
                                                  int M, int N, int K) {
    __shared__ __align__(16) u16 As[128 * 64];
    __shared__ __align__(16) u16 Bs[128 * 64];
    int tid = threadIdx.x, lane = tid & 63, wave = tid >> 6;
    int quad = lane >> 4, ln = lane & 15;
    int m0 = blockIdx.x * 128, n0 = blockIdx.y * 128;
    int wm = (wave & 1) * 64, wn = (wave >> 1) * 64;
    f32x4 acc[4][4] = {};

    for (int k0 = 0; k0 < K; k0 += 64) {
        __syncthreads();
#pragma unroll
        for (int c = 0; c < 4; c++) {
            int chunk = c * 256 + wave * 64 + lane;  // uniform base + lane
            int r = chunk >> 3, kc = chunk & 7;
            gld16(A + (size_t)(m0 + r) * K + k0 + kc * 8, As + chunk * 8);
            gld16(Bt + (size_t)(n0 + r) * K + k0 + kc * 8, Bs + chunk * 8);
        }
        __syncthreads();
        bf16x8 af[4][2], bf[4][2];
#pragma unroll
        for (int i = 0; i < 4; i++) {
#pragma unroll
            for (int kk = 0; kk < 2; kk++) {
                af[i][kk] = *(const bf16x8*)(As + (wm + i * 16 + ln) * 64 + kk * 32 + quad * 8);
                bf[i][kk] = *(const bf16x8*)(Bs + (wn + i * 16 + ln) * 64 + kk * 32 + quad * 8);
            }
        }
#pragma unroll
        for (int i = 0; i < 4; i++)
#pragma unroll
            for (int j = 0; j < 4; j++) {
                acc[i][j] = MFMA16(af[i][0], bf[j][0], acc[i][j]);
                acc[i][j] = MFMA16(af[i][1], bf[j][1], acc[i][j]);
            }
    }

#pragma unroll
    for (int i = 0; i < 4; i++)
#pragma unroll
        for (int j = 0; j < 4; j++) {
            int col = n0 + wn + j * 16 + ln;
            float bv = (MODE >= 1) ? bias[col] : 0.f;
#pragma unroll
            for (int r = 0; r < 4; r++) {
                int row = m0 + wm + i * 16 + quad * 4 + r;
                float v = acc[i][j][r] + bv;
                if (MODE == 1) v = fmaxf(v, 0.f);
                ((u16*)Cout)[(size_t)row * N + col] = f2bf(v);
            }
        }
}

// ---------------------------------------------------------------------------
// 3b) Big GEMM: 256x256 tile, BK=64, 8 waves (2Mx4N), 8-phase counted-vmcnt
//     schedule (T2 swizzle + T3/T4 + T5). fp32 out + bias + fused per-strip
//     logsumexp partials (float2 {max, sumexp} per row per 64-col strip).
//
// LDS layout (u16 units), 128 KiB total:
//   A: half h (rows h*128..h*128+127), buf b: off = h*16384 + b*8192 + row*64 + col
//   B: 32768 + same
// Swizzle: element col8-block kc stored at kc^(row&7); since frag rows step by
// 16, read-side XOR is the per-lane constant (ln&7) folded into base pointers.
//
// Steady-state prefetch schedule (tiles 2j,2j+1 computed from buf0,buf1):
//   ph1: A1(2j+1)   ph3: B0(2j+2)   ph4: B1,A0(2j+2)  vmcnt(6)
//   ph5: A1(2j+2)   ph7: B0(2j+3)   ph8: B1,A0(2j+3)  vmcnt(6)
// vmcnt(6) at ph4 => tile 2j+1 fully landed; at ph8 => tile 2j+2 landed.
// Region-liveness: each region's last ds_read is consumed (lgkm wait before
// that phase's MFMA) before the phase-end barrier preceding its overwrite.
// ---------------------------------------------------------------------------
__device__ __forceinline__ void ldA4(bf16x8 (&fa)[4][2], const u16* p0, const u16* p1, int off) {
#pragma unroll
    for (int ii = 0; ii < 4; ++ii) {
        fa[ii][0] = *(const bf16x8*)(p0 + off + ii * 1024);
        fa[ii][1] = *(const bf16x8*)(p1 + off + ii * 1024);
    }
}
__device__ __forceinline__ void ldB2(bf16x8 (&fb)[2][2], const u16* p0, const u16* p1, int off) {
#pragma unroll
    for (int jj = 0; jj < 2; ++jj) {
        fb[jj][0] = *(const bf16x8*)(p0 + off + jj * 1024);
        fb[jj][1] = *(const bf16x8*)(p1 + off + jj * 1024);
    }
}
__device__ __forceinline__ void mfma_quad(f32x4 (&acc)[8][4], const bf16x8 (&A)[4][2],
                                          const bf16x8 (&B)[2][2], int qr, int qc) {
    __builtin_amdgcn_s_setprio(1);
#pragma unroll
    for (int ii = 0; ii < 4; ++ii)
#pragma unroll
        for (int jj = 0; jj < 2; ++jj) {
            f32x4 c = acc[qr * 4 + ii][qc * 2 + jj];
            c = MFMA16(A[ii][0], B[jj][0], c);
            c = MFMA16(A[ii][1], B[jj][1], c);
            acc[qr * 4 + ii][qc * 2 + jj] = c;
        }
    __builtin_amdgcn_s_setprio(0);
}

__global__ __launch_bounds__(512, 2) void gemm256_lse(const u16* __restrict__ A,
                                                      const u16* __restrict__ Bt,
                                                      float* __restrict__ C,
                                                      const float* __restrict__ bias,
                                                      float2* __restrict__ pl,
                                                      int M, int N, int K) {
    __shared__ __align__(16) u16 lds[65536];  // 128 KiB
    const int tid = threadIdx.x;
    const int lane = tid & 63;
    const int wave = tid >> 6;
    const int quad = lane >> 4, ln = lane & 15;
    const int wm = wave >> 2, wn = wave & 3;  // 2M x 4N waves

    const int bid = blockIdx.x;
    const int mtile = bid & 15, ntile = bid >> 4;  // grid = 16 * (N/256)
    const int m0 = mtile << 8, n0 = ntile << 8;

    // ---- staging (global_load_lds, linear LDS dest, inverse-swizzled source)
    auto stageA = [&](int h, int b, int kt) {
#pragma unroll
        for (int l = 0; l < 2; ++l) {
            int chunk = l * 512 + tid;  // 0..1023 -> 128 rows x 8 col-blocks
            int r = chunk >> 3, kc = chunk & 7;
            int kcs = kc ^ (r & 7);
            gld16(A + (size_t)(m0 + h * 128 + r) * K + kt * 64 + kcs * 8,
                  lds + h * 16384 + b * 8192 + chunk * 8);
        }
    };
    auto stageB = [&](int h, int b, int kt) {
#pragma unroll
        for (int l = 0; l < 2; ++l) {
            int chunk = l * 512 + tid;
            int r = chunk >> 3, kc = chunk & 7;
            int kcs = kc ^ (r & 7);
            gld16(Bt + (size_t)(n0 + h * 128 + r) * K + kt * 64 + kcs * 8,
                  lds + 32768 + h * 16384 + b * 8192 + chunk * 8);
        }
    };

    // ---- fragment base pointers (swizzle XOR folded in: row&7 == ln&7)
    const int c80 = ((0 * 4 + quad) ^ (ln & 7)) * 8;
    const int c81 = ((1 * 4 + quad) ^ (ln & 7)) * 8;
    const u16* pA0 = lds + wm * 16384 + ln * 64 + c80;
    const u16* pA1 = lds + wm * 16384 + ln * 64 + c81;
    const u16* pB0 = lds + 32768 + (wn >> 1) * 16384 + ((wn & 1) * 64 + ln) * 64 + c80;
    const u16* pB1 = lds + 32768 + (wn >> 1) * 16384 + ((wn & 1) * 64 + ln) * 64 + c81;

    f32x4 acc[8][4] = {};

    // ---- prologue: tile0 (buf0) fully + tile1 (buf1) B0,B1,A0. A1(1) at ph1.
    stageA(0, 0, 0); stageA(1, 0, 0); stageB(0, 0, 0); stageB(1, 0, 0);
    stageB(0, 1, 1); stageB(1, 1, 1); stageA(0, 1, 1);
    VMW(6);  // tile0's 8 loads landed; 6 outstanding = tile1's B0,B1,A0
    SBAR();

    const int NIT = K >> 7;  // iterations of 2 K-tiles
#pragma unroll 1
    for (int j = 0; j < NIT; ++j) {
        const int t0 = 2 * j;
        const bool pf = (j < NIT - 1);
        bf16x8 fa[4][2], fbA[2][2], fbB[2][2];

        // ================= K-tile t0 (buf0) =================
        // ph1: quadrant (0,0)
        ldA4(fa, pA0, pA1, 0);
        ldB2(fbA, pB0, pB1, 0);
        stageA(1, 1, t0 + 1);
        SBAR();
        mfma_quad(acc, fa, fbA, 0, 0);
        SBAR();
        // ph2: quadrant (0,1)
        ldB2(fbB, pB0, pB1, 2048);
        SBAR();
        mfma_quad(acc, fa, fbB, 0, 1);
        SBAR();
        // ph3: quadrant (1,1)
        ldA4(fa, pA0, pA1, 4096);
        if (pf) stageB(0, 0, t0 + 2);
        SBAR();
        mfma_quad(acc, fa, fbB, 1, 1);
        SBAR();
        // ph4: quadrant (1,0)
        if (pf) { stageB(1, 0, t0 + 2); stageA(0, 0, t0 + 2); }
        SBAR();
        mfma_quad(acc, fa, fbA, 1, 0);
        if (pf) { VMW(6); } else { VMW(0); }  // tile t0+1 landed
        SBAR();

        // ================= K-tile t0+1 (buf1) =================
        // ph5
        ldA4(fa, pA0, pA1, 8192);
        ldB2(fbA, pB0, pB1, 8192);
        if (pf) stageA(1, 0, t0 + 2);
        SBAR();
        mfma_quad(acc, fa, fbA, 0, 0);
        SBAR();
        // ph6
        ldB2(fbB, pB0, pB1, 8192 + 2048);
        SBAR();
        mfma_quad(acc, fa, fbB, 0, 1);
        SBAR();
        // ph7
        ldA4(fa, pA0, pA1, 8192 + 4096);
        if (pf) stageB(0, 1, t0 + 3);
        SBAR();
        mfma_quad(acc, fa, fbB, 1, 1);
        SBAR();
        // ph8
        if (pf) { stageB(1, 1, t0 + 3); stageA(0, 1, t0 + 3); }
        SBAR();
        mfma_quad(acc, fa, fbA, 1, 0);
        if (pf) VMW(6);  // tile t0+2 landed
        SBAR();
    }

    // ---- epilogue: bias + fp32 store + per-(row, 64-col strip) LSE partial
    const int strips = N >> 6;
    float bv[4];
#pragma unroll
    for (int jj = 0; jj < 4; ++jj) bv[jj] = bias[n0 + wn * 64 + jj * 16 + ln];

#pragma unroll
    for (int ii = 0; ii < 8; ++ii) {
#pragma unroll
        for (int rr = 0; rr < 4; ++rr) {
            int row = m0 + wm * 128 + ii * 16 + quad * 4 + rr;
            float v0 = acc[ii][0][rr] + bv[0];
            float v1 = acc[ii][1][rr] + bv[1];
            float v2 = acc[ii][2][rr] + bv[2];
            float v3 = acc[ii][3][rr] + bv[3];
            float* cp = C + (size_t)row * N + n0 + wn * 64 + ln;
            cp[0] = v0; cp[16] = v1; cp[32] = v2; cp[48] = v3;
            float mx = fmaxf(fmaxf(v0, v1), fmaxf(v2, v3));
#pragma unroll
            for (int off = 1; off < 16; off <<= 1) mx = fmaxf(mx, __shfl_xor(mx, off, 16));
            float s = __expf(v0 - mx) + __expf(v1 - mx) + __expf(v2 - mx) + __expf(v3 - mx);
#pragma unroll
            for (int off = 1; off < 16; off <<= 1) s += __shfl_xor(s, off, 16);
            if (ln == 0) pl[(size_t)row * strips + (ntile << 2) + wn] = make_float2(mx, s);
        }
    }
}

// ---------------------------------------------------------------------------
// 4) flash attention. qkv bf16 [4096][3072] (q|k|v each 1024 = h*64+d).
//    grid (T/64=16, B*H=64); block 256 = 4 waves x 16 q-rows.
//    scores scaled by sqrt(HS)=8 (ref multiplies by HS**0.5). causal.
//    out o bf16 [4096][1024] at col h*64+d (== concat-heads layout).
// ---------------------------------------------------------------------------
__global__ __launch_bounds__(256, 2) void attn_kernel(const u16* __restrict__ qkv,
                                                      u16* __restrict__ o) {
    __shared__ __align__(16) u16 kt[64 * 64];
    __shared__ __align__(16) u16 vt[64 * 64];   // transposed: vt[d][s]
    __shared__ __align__(16) u16 pt[4][16 * 64];
    int tid = threadIdx.x, lane = tid & 63, wave = tid >> 6;
    int quad = lane >> 4, ln = lane & 15;
    int it = blockIdx.x;
    int b = blockIdx.y >> 4, hh = blockIdx.y & 15;
    int t0 = it * 64;

    bf16x8 qf[2];
    {
        const u16* qb = qkv + (size_t)(b * 1024 + t0 + wave * 16 + ln) * 3072 + hh * 64 + quad * 8;
        qf[0] = *(const bf16x8*)(qb);
        qf[1] = *(const bf16x8*)(qb + 32);
    }
    f32x4 Oacc[4] = {};
    float m_run[4], l_run[4];
#pragma unroll
    for (int r = 0; r < 4; r++) { m_run[r] = -1e30f; l_run[r] = 0.f; }

    for (int j = 0; j <= it; j++) {
        __syncthreads();
        {   // stage K tile [s][d] and V^T tile [d][s]
            int r = tid >> 2, cg = tid & 3;
            const u16* krow = qkv + (size_t)(b * 1024 + j * 64 + r) * 3072 + 1024 + hh * 64 + cg * 16;
            uint4 k0 = *(const uint4*)(krow);
            uint4 k1 = *(const uint4*)(krow + 8);
            *(uint4*)(kt + r * 64 + cg * 16) = k0;
            *(uint4*)(kt + r * 64 + cg * 16 + 8) = k1;
            union { uint4 v; u16 s[8]; } v0, v1;
            v0.v = *(const uint4*)(krow + 1024);
            v1.v = *(const uint4*)(krow + 1024 + 8);
#pragma unroll
            for (int i = 0; i < 8; i++) vt[(cg * 16 + i) * 64 + r] = v0.s[i];
#pragma unroll
            for (int i = 0; i < 8; i++) vt[(cg * 16 + 8 + i) * 64 + r] = v1.s[i];
        }
        __syncthreads();

        f32x4 S[4];
#pragma unroll
        for (int ct = 0; ct < 4; ct++) {
            f32x4 s = {};
            bf16x8 kf0 = *(const bf16x8*)(kt + (ct * 16 + ln) * 64 + quad * 8);
            bf16x8 kf1 = *(const bf16x8*)(kt + (ct * 16 + ln) * 64 + 32 + quad * 8);
            s = MFMA16(qf[0], kf0, s);
            s = MFMA16(qf[1], kf1, s);
            S[ct] = s;
        }
        // scale + causal mask
#pragma unroll
        for (int ct = 0; ct < 4; ct++)
#pragma unroll
            for (int r = 0; r < 4; r++) {
                int srow = t0 + wave * 16 + quad * 4 + r;
                int scol = j * 64 + ct * 16 + ln;
                S[ct][r] = (scol <= srow) ? S[ct][r] * 8.0f : -1e30f;
            }
        // online softmax (rows live in 16-lane groups: shuffle width 16)
        float alpha[4];
#pragma unroll
        for (int r = 0; r < 4; r++) {
            float mx = fmaxf(fmaxf(S[0][r], S[1][r]), fmaxf(S[2][r], S[3][r]));
#pragma unroll
            for (int off = 1; off < 16; off <<= 1) mx = fmaxf(mx, __shfl_xor(mx, off, 16));
            float mn = fmaxf(m_run[r], mx);
            alpha[r] = __expf(m_run[r] - mn);
            float ssum = 0.f;
#pragma unroll
            for (int ct = 0; ct < 4; ct++) {
                float p = __expf(S[ct][r] - mn);
                S[ct][r] = p;
                ssum += p;
            }
#pragma unroll
            for (int off = 1; off < 16; off <<= 1) ssum += __shfl_xor(ssum, off, 16);
            l_run[r] = l_run[r] * alpha[r] + ssum;
            m_run[r] = mn;
        }
        // P -> wave-private LDS (C-layout rows quad*4+r), reread as A-frags
        u16* ptw = pt[wave];
#pragma unroll
        for (int ct = 0; ct < 4; ct++)
#pragma unroll
            for (int r = 0; r < 4; r++)
                ptw[(quad * 4 + r) * 64 + ct * 16 + ln] = f2bf(S[ct][r]);
#pragma unroll
        for (int dt = 0; dt < 4; dt++)
#pragma unroll
            for (int r = 0; r < 4; r++) Oacc[dt][r] *= alpha[r];
        bf16x8 pf0 = *(const bf16x8*)(ptw + ln * 64 + quad * 8);
        bf16x8 pf1 = *(const bf16x8*)(ptw + ln * 64 + 32 + quad * 8);
#pragma unroll
        for (int dt = 0; dt < 4; dt++) {
            bf16x8 vf0 = *(const bf16x8*)(vt + (dt * 16 + ln) * 64 + quad * 8);
            bf16x8 vf1 = *(const bf16x8*)(vt + (dt * 16 + ln) * 64 + 32 + quad * 8);
            Oacc[dt] = MFMA16(pf0, vf0, Oacc[dt]);
            Oacc[dt] = MFMA16(pf1, vf1, Oacc[dt]);
        }
    }
#pragma unroll
    for (int r = 0; r < 4; r++) l_run[r] = 1.0f / l_run[r];
#pragma unroll
    for (int dt = 0; dt < 4; dt++)
#pragma unroll
        for (int r = 0; r < 4; r++) {
            int row = b * 1024 + t0 + wave * 16 + quad * 4 + r;
            o[(size_t)row * 1024 + hh * 64 + dt * 16 + ln] = f2bf(Oacc[dt][r] * l_run[r]);
        }
}

// ---------------------------------------------------------------------------
// 5) loss from fused LSE partials: combine 500 (m,s) pairs per row
// ---------------------------------------------------------------------------
__global__ __launch_bounds__(256) void lse_loss(const float2* __restrict__ pl,
                                                const float* __restrict__ logits,
                                                const int* __restrict__ y,
                                                float* __restrict__ rl) {
    int row = blockIdx.x;
    const float2* p = pl + (size_t)row * 500;
    float m = -1e30f, s = 0.f;
    for (int i = threadIdx.x; i < 500; i += 256) {
        float2 v = p[i];
        float mn = fmaxf(m, v.x);
        s = s * __expf(m - mn) + v.y * __expf(v.x - mn);
        m = mn;
    }
#pragma unroll
    for (int off = 1; off < 64; off <<= 1) {
        float m2 = __shfl_xor(m, off);
        float s2 = __shfl_xor(s, off);
        float mn = fmaxf(m, m2);
        s = s * __expf(m - mn) + s2 * __expf(m2 - mn);
        m = mn;
    }
    __shared__ float sm[4], ss[4];
    int wv = threadIdx.x >> 6;
    if ((threadIdx.x & 63) == 0) { sm[wv] = m; ss[wv] = s; }
    __syncthreads();
    if (threadIdx.x == 0) {
        float M = sm[0], S = ss[0];
#pragma unroll
        for (int w = 1; w < 4; w++) {
            float mn = fmaxf(M, sm[w]);
            S = S * __expf(M - mn) + ss[w] * __expf(sm[w] - mn);
            M = mn;
        }
        rl[row] = (M + __logf(S)) - logits[(size_t)row * 32000 + y[row]];
    }
}

__global__ void loss_final(const float* __restrict__ rl, float* __restrict__ out) {
    float s = 0.f;
    for (int i = threadIdx.x; i < 4096; i += 256) s += rl[i];
#pragma unroll
    for (int off = 1; off < 64; off <<= 1) s += __shfl_xor(s, off);
    __shared__ float a[4];
    if ((threadIdx.x & 63) == 0) a[threadIdx.x >> 6] = s;
    __syncthreads();
    if (threadIdx.x == 0) out[0] = (a[0] + a[1] + a[2] + a[3]) * (1.0f / 4096.0f);
}

// ---------------------------------------------------------------------------
extern "C" void kernel_launch(void* const* d_in, const int* in_sizes, int n_in,
                              void* d_out, int out_size, void* d_ws, size_t ws_size,
                              hipStream_t stream) {
    const int* x = (const int*)d_in[0];
    const int* y = (const int*)d_in[1];
    const float* tok = (const float*)d_in[2];
    const float* pos = (const float*)d_in[3];
    const float* Wq = (const float*)d_in[4];
    const float* Wk = (const float*)d_in[5];
    const float* Wv = (const float*)d_in[6];
    const float* ffw = (const float*)d_in[7];
    const float* ffb = (const float*)d_in[8];
    const float* fcw = (const float*)d_in[9];
    const float* fcb = (const float*)d_in[10];
    float* out = (float*)d_out;  // logits [4096*32000] then loss [1]

    u16* ws = (u16*)d_ws;
    u16* h = ws;                                  // 4096x1024
    u16* wqkvt = h + (size_t)4096 * 1024;         // 3072x1024 (q|k|v rows)
    u16* qkv = wqkvt + (size_t)3072 * 1024;       // 4096x3072
    u16* oo = qkv + (size_t)4096 * 3072;          // 4096x1024
    u16* ffwt = oo + (size_t)4096 * 1024;         // 1024x1024
    u16* ffact = ffwt + (size_t)1024 * 1024;      // 4096x1024
    u16* fcwt = ffact + (size_t)4096 * 1024;      // 32000x1024
    float2* pl = (float2*)(fcwt + (size_t)32000 * 1024);     // 4096x500 LSE partials
    float* rowloss = (float*)(pl + (size_t)4096 * 500);      // 4096

    // 1) embedding
    embed_kernel<<<4096, 256, 0, stream>>>(x, tok, pos, h);

    // 2) weight repacks (per call; inputs are re-restored each timed launch)
    transpose_f32_bf16<<<dim3(16, 1, 16), 256, 0, stream>>>(Wq, wqkvt, 1024, 64);
    transpose_f32_bf16<<<dim3(16, 1, 16), 256, 0, stream>>>(Wk, wqkvt + (size_t)1024 * 1024, 1024, 64);
    transpose_f32_bf16<<<dim3(16, 1, 16), 256, 0, stream>>>(Wv, wqkvt + (size_t)2048 * 1024, 1024, 64);
    transpose_f32_bf16<<<dim3(16, 16, 1), 256, 0, stream>>>(ffw, ffwt, 1024, 1024);
    transpose_f32_bf16<<<dim3(16, 500, 1), 256, 0, stream>>>(fcw, fcwt, 1024, 32000);

    // 3) qkv = h @ [Wq|Wk|Wv]   M=4096 N=3072 K=1024
    gemm_bt<0><<<dim3(32, 24), 256, 0, stream>>>(h, wqkvt, qkv, nullptr, 4096, 3072, 1024);

    // 4) attention -> oo
    attn_kernel<<<dim3(16, 64), 256, 0, stream>>>(qkv, oo);

    // 5) ff = relu(oo @ ff_w + ff_b)
    gemm_bt<1><<<dim3(32, 8), 256, 0, stream>>>(oo, ffwt, ffact, ffb, 4096, 1024, 1024);

    // 6) logits = ffact @ fc_w + fc_b  (fp32 to d_out) + fused LSE partials
    //    grid: 16 mtiles x 125 ntiles (mtile = bid&15 -> consecutive blocks
    //    share the B-panel for L2 reuse)
    gemm256_lse<<<2000, 512, 0, stream>>>(ffact, fcwt, out, fcb, pl, 4096, 32000, 1024);

    // 7) loss from partials (16 MB read instead of 524 MB logits re-read)
    lse_loss<<<4096, 256, 0, stream>>>(pl, out, y, rowloss);
    loss_final<<<1, 256, 0, stream>>>(rowloss, out + (size_t)4096 * 32000);
}